// Round 1
// baseline (207.141 us; speedup 1.0000x reference)
//
#include <hip/hip_runtime.h>
#include <hip/hip_bf16.h>
#include <math.h>

typedef __bf16 bf16;
typedef __bf16 bf16x8 __attribute__((ext_vector_type(8)));
typedef __bf16 bf16x4 __attribute__((ext_vector_type(4)));
typedef float f32x4 __attribute__((ext_vector_type(4)));

#define SEQ 1024
#define DIMSZ 1024
#define NHEADS 16
#define HEADDIM 64
#define BATCH 4

// ---------------- fp32 -> bf16 conversion (optionally scaled) ----------------
__global__ void cvt_f32_bf16(const float4* __restrict__ src, bf16x4* __restrict__ dst,
                             int n4, float scale) {
    int i = blockIdx.x * blockDim.x + threadIdx.x;
    if (i < n4) {
        float4 v = src[i];
        bf16x4 o;
        o[0] = (bf16)(v.x * scale);
        o[1] = (bf16)(v.y * scale);
        o[2] = (bf16)(v.z * scale);
        o[3] = (bf16)(v.w * scale);
        dst[i] = o;
    }
}

// LDS fragment read: 8 contiguous bf16 at [row0 + (lane&15)][k0 + (lane>>4)*8],
// leading dim 72 elements (144B, 16B-aligned rows, ~2-way bank conflicts only).
#define LDT 72
__device__ inline bf16x8 ldsfrag(const bf16* base, int row0, int k0, int lane) {
    return *reinterpret_cast<const bf16x8*>(base + (row0 + (lane & 15)) * LDT + k0 + ((lane >> 4) << 3));
}

// ---------------- bf16 GEMM: C[M][N] = A[M][K] @ B[N][K]^T + bias ----------------
// 128x128 tile, BK=64, 256 threads (4 waves, each computing a 64x64 quadrant).
template <int OUT_F32>
__global__ __launch_bounds__(256) void gemm_bt(
    const bf16* __restrict__ A, const bf16* __restrict__ Bm,
    const float* __restrict__ bias, float bias_scale,
    void* __restrict__ Cv, int M, int N, int K)
{
    __shared__ __align__(16) bf16 As[128 * LDT];
    __shared__ __align__(16) bf16 Bs[128 * LDT];

    const int nbn = N >> 7;
    const int bm = blockIdx.x / nbn, bn = blockIdx.x % nbn;
    const int m0 = bm << 7, n0 = bn << 7;
    const int tid = threadIdx.x, lane = tid & 63, wid = tid >> 6;
    const int wr = wid >> 1, wc = wid & 1;

    f32x4 acc[4][4] = {};

    for (int kt = 0; kt < K; kt += 64) {
        // stage 128x64 A-tile and B-tile: 1024 16B-chunks each -> 4 per thread
        #pragma unroll
        for (int c = 0; c < 4; ++c) {
            int id = tid + (c << 8);
            int row = id >> 3, c8 = (id & 7) << 3;
            *reinterpret_cast<bf16x8*>(&As[row * LDT + c8]) =
                *reinterpret_cast<const bf16x8*>(&A[(size_t)(m0 + row) * K + kt + c8]);
            *reinterpret_cast<bf16x8*>(&Bs[row * LDT + c8]) =
                *reinterpret_cast<const bf16x8*>(&Bm[(size_t)(n0 + row) * K + kt + c8]);
        }
        __syncthreads();

        bf16x8 af[4][2], bfr[4][2];
        #pragma unroll
        for (int m = 0; m < 4; ++m)
            #pragma unroll
            for (int h2 = 0; h2 < 2; ++h2)
                af[m][h2] = ldsfrag(As, wr * 64 + m * 16, h2 * 32, lane);
        #pragma unroll
        for (int n = 0; n < 4; ++n)
            #pragma unroll
            for (int h2 = 0; h2 < 2; ++h2)
                bfr[n][h2] = ldsfrag(Bs, wc * 64 + n * 16, h2 * 32, lane);

        #pragma unroll
        for (int m = 0; m < 4; ++m)
            #pragma unroll
            for (int n = 0; n < 4; ++n)
                #pragma unroll
                for (int h2 = 0; h2 < 2; ++h2)
                    acc[m][n] = __builtin_amdgcn_mfma_f32_16x16x32_bf16(
                        af[m][h2], bfr[n][h2], acc[m][n], 0, 0, 0);
        __syncthreads();
    }

    // epilogue: C/D layout col = lane&15, row = (lane>>4)*4 + reg
    #pragma unroll
    for (int m = 0; m < 4; ++m) {
        #pragma unroll
        for (int n = 0; n < 4; ++n) {
            int rbase = m0 + wr * 64 + m * 16 + ((lane >> 4) << 2);
            int col = n0 + wc * 64 + n * 16 + (lane & 15);
            float bv = bias[col] * bias_scale;
            #pragma unroll
            for (int r = 0; r < 4; ++r) {
                float v = acc[m][n][r] + bv;
                if (OUT_F32)
                    ((float*)Cv)[(size_t)(rbase + r) * N + col] = v;
                else
                    ((bf16*)Cv)[(size_t)(rbase + r) * N + col] = (bf16)v;
            }
        }
    }
}

// ---------------- fused decay-masked attention ----------------
// One block per (b, h, qblock-of-64). 4 waves, each owns 16 q-rows.
// Q,K staged row-major in LDS; V staged transposed; P routed via LDS.
// decaymask read fp32 straight from HBM (read exactly once).
__global__ __launch_bounds__(256) void attn_kernel(
    const bf16* __restrict__ Qg, const bf16* __restrict__ Kg, const bf16* __restrict__ Vg,
    const float* __restrict__ mask, bf16* __restrict__ Og)
{
    __shared__ __align__(16) bf16 Qs[64 * LDT];
    __shared__ __align__(16) bf16 Ks[64 * LDT];
    __shared__ __align__(16) bf16 VTs[64 * LDT];
    __shared__ __align__(16) bf16 Ps[64 * LDT];

    const int qblk = blockIdx.x & 15;
    const int h = (blockIdx.x >> 4) & 15;
    const int b = blockIdx.x >> 8;
    const int tid = threadIdx.x, lane = tid & 63, wid = tid >> 6;
    const int qbase = qblk << 6;

    // stage Q tile (64 rows x 64 dims): 512 chunks -> 2 per thread
    #pragma unroll
    for (int c = 0; c < 2; ++c) {
        int id = tid + (c << 8);
        int row = id >> 3, c8 = (id & 7) << 3;
        *reinterpret_cast<bf16x8*>(&Qs[row * LDT + c8]) =
            *reinterpret_cast<const bf16x8*>(&Qg[(size_t)(b * SEQ + qbase + row) * DIMSZ + h * HEADDIM + c8]);
    }

    float m_run[4], l_run[4];
    f32x4 oacc[4] = {};
    #pragma unroll
    for (int r = 0; r < 4; ++r) { m_run[r] = -3.0e38f; l_run[r] = 0.f; }

    const float* mh = mask + (size_t)h * SEQ * SEQ;
    const int rowq0 = qbase + wid * 16 + ((lane >> 4) << 2);  // global q row for reg 0

    for (int kt = 0; kt < SEQ; kt += 64) {
        // stage K tile + transposed V tile
        #pragma unroll
        for (int c = 0; c < 2; ++c) {
            int id = tid + (c << 8);
            int row = id >> 3, c8 = (id & 7) << 3;
            *reinterpret_cast<bf16x8*>(&Ks[row * LDT + c8]) =
                *reinterpret_cast<const bf16x8*>(&Kg[(size_t)(b * SEQ + kt + row) * DIMSZ + h * HEADDIM + c8]);
            bf16x8 v8 = *reinterpret_cast<const bf16x8*>(&Vg[(size_t)(b * SEQ + kt + row) * DIMSZ + h * HEADDIM + c8]);
            #pragma unroll
            for (int j = 0; j < 8; ++j)
                VTs[(c8 + j) * LDT + row] = v8[j];
        }
        __syncthreads();

        // S strip (16 q-rows x 64 keys) = Q @ K^T  (q pre-scaled by 1/8)
        bf16x8 aq[2];
        #pragma unroll
        for (int h2 = 0; h2 < 2; ++h2) aq[h2] = ldsfrag(Qs, wid * 16, h2 * 32, lane);
        f32x4 sacc[4] = {};
        #pragma unroll
        for (int ct = 0; ct < 4; ++ct)
            #pragma unroll
            for (int h2 = 0; h2 < 2; ++h2)
                sacc[ct] = __builtin_amdgcn_mfma_f32_16x16x32_bf16(
                    aq[h2], ldsfrag(Ks, ct * 16, h2 * 32, lane), sacc[ct], 0, 0, 0);

        // multiply by decay mask (fp32, straight from HBM)
        float sv[4][4];
        const int kc0 = kt + (lane & 15);
        #pragma unroll
        for (int ct = 0; ct < 4; ++ct)
            #pragma unroll
            for (int r = 0; r < 4; ++r)
                sv[ct][r] = sacc[ct][r] * mh[(size_t)(rowq0 + r) * SEQ + kc0 + ct * 16];

        // online softmax: row stats via shfl_xor over the 16-lane group
        float m_new[4], scl[4];
        #pragma unroll
        for (int r = 0; r < 4; ++r) {
            float mx = fmaxf(fmaxf(sv[0][r], sv[1][r]), fmaxf(sv[2][r], sv[3][r]));
            #pragma unroll
            for (int off = 1; off < 16; off <<= 1)
                mx = fmaxf(mx, __shfl_xor(mx, off, 64));
            m_new[r] = fmaxf(m_run[r], mx);
            scl[r] = __expf(m_run[r] - m_new[r]);
        }
        float pl[4][4];
        #pragma unroll
        for (int r = 0; r < 4; ++r) {
            float s = 0.f;
            #pragma unroll
            for (int ct = 0; ct < 4; ++ct) {
                float p = __expf(sv[ct][r] - m_new[r]);
                pl[ct][r] = p;
                s += p;
            }
            #pragma unroll
            for (int off = 1; off < 16; off <<= 1)
                s += __shfl_xor(s, off, 64);
            l_run[r] = l_run[r] * scl[r] + s;
            m_run[r] = m_new[r];
        }
        #pragma unroll
        for (int ot = 0; ot < 4; ++ot)
            #pragma unroll
            for (int r = 0; r < 4; ++r)
                oacc[ot][r] *= scl[r];

        // write P strip to LDS as bf16 (A-operand for PV)
        #pragma unroll
        for (int ct = 0; ct < 4; ++ct)
            #pragma unroll
            for (int r = 0; r < 4; ++r)
                Ps[(wid * 16 + ((lane >> 4) << 2) + r) * LDT + ct * 16 + (lane & 15)] = (bf16)pl[ct][r];
        __syncthreads();

        // O strip += P @ V
        bf16x8 pf[2];
        #pragma unroll
        for (int h2 = 0; h2 < 2; ++h2) pf[h2] = ldsfrag(Ps, wid * 16, h2 * 32, lane);
        #pragma unroll
        for (int ot = 0; ot < 4; ++ot)
            #pragma unroll
            for (int h2 = 0; h2 < 2; ++h2)
                oacc[ot] = __builtin_amdgcn_mfma_f32_16x16x32_bf16(
                    pf[h2], ldsfrag(VTs, ot * 16, h2 * 32, lane), oacc[ot], 0, 0, 0);
        __syncthreads();
    }

    // epilogue: normalize and write attention output (bf16)
    #pragma unroll
    for (int ot = 0; ot < 4; ++ot) {
        #pragma unroll
        for (int r = 0; r < 4; ++r) {
            int qrow = rowq0 + r;
            int col = h * HEADDIM + ot * 16 + (lane & 15);
            Og[(size_t)(b * SEQ + qrow) * DIMSZ + col] = (bf16)(oacc[ot][r] / l_run[r]);
        }
    }
}

extern "C" void kernel_launch(void* const* d_in, const int* in_sizes, int n_in,
                              void* d_out, int out_size, void* d_ws, size_t ws_size,
                              hipStream_t stream) {
    const float* x    = (const float*)d_in[0];
    const float* mask = (const float*)d_in[1];
    const float* wq   = (const float*)d_in[2];
    const float* bq   = (const float*)d_in[3];
    const float* wk   = (const float*)d_in[4];
    const float* bk   = (const float*)d_in[5];
    const float* wv   = (const float*)d_in[6];
    const float* bv   = (const float*)d_in[7];
    const float* wo   = (const float*)d_in[8];
    const float* bo   = (const float*)d_in[9];
    float* out = (float*)d_out;

    const size_t MTOK = (size_t)BATCH * SEQ;           // 4096
    char* ws = (char*)d_ws;
    bf16* xb  = (bf16*)ws; ws += MTOK * DIMSZ * 2;     // 8 MB
    bf16* wqb = (bf16*)ws; ws += (size_t)DIMSZ * DIMSZ * 2;
    bf16* wkb = (bf16*)ws; ws += (size_t)DIMSZ * DIMSZ * 2;
    bf16* wvb = (bf16*)ws; ws += (size_t)DIMSZ * DIMSZ * 2;
    bf16* wob = (bf16*)ws; ws += (size_t)DIMSZ * DIMSZ * 2;
    bf16* qb  = (bf16*)ws; ws += MTOK * DIMSZ * 2;
    bf16* kb  = (bf16*)ws; ws += MTOK * DIMSZ * 2;
    bf16* vb  = (bf16*)ws; ws += MTOK * DIMSZ * 2;
    bf16* aob = (bf16*)ws; ws += MTOK * DIMSZ * 2;     // total 48 MB

    // conversions (fold 1/sqrt(HEADDIM)=1/8 into wq and bq)
    int n4x = (int)(MTOK * DIMSZ / 4);
    cvt_f32_bf16<<<(n4x + 255) / 256, 256, 0, stream>>>((const float4*)x, (bf16x4*)xb, n4x, 1.f);
    int n4w = DIMSZ * DIMSZ / 4;
    int gw = (n4w + 255) / 256;
    cvt_f32_bf16<<<gw, 256, 0, stream>>>((const float4*)wq, (bf16x4*)wqb, n4w, 0.125f);
    cvt_f32_bf16<<<gw, 256, 0, stream>>>((const float4*)wk, (bf16x4*)wkb, n4w, 1.f);
    cvt_f32_bf16<<<gw, 256, 0, stream>>>((const float4*)wv, (bf16x4*)wvb, n4w, 1.f);
    cvt_f32_bf16<<<gw, 256, 0, stream>>>((const float4*)wo, (bf16x4*)wob, n4w, 1.f);

    // q/k/v projections (bf16 out)
    int gblk = (int)(MTOK / 128) * (DIMSZ / 128);  // 256
    gemm_bt<0><<<gblk, 256, 0, stream>>>(xb, wqb, bq, 0.125f, qb, (int)MTOK, DIMSZ, DIMSZ);
    gemm_bt<0><<<gblk, 256, 0, stream>>>(xb, wkb, bk, 1.f, kb, (int)MTOK, DIMSZ, DIMSZ);
    gemm_bt<0><<<gblk, 256, 0, stream>>>(xb, wvb, bv, 1.f, vb, (int)MTOK, DIMSZ, DIMSZ);

    // fused attention: B*H*(SEQ/64) = 1024 blocks
    attn_kernel<<<BATCH * NHEADS * (SEQ / 64), 256, 0, stream>>>(qb, kb, vb, mask, aob);

    // output projection (fp32 out + bias)
    gemm_bt<1><<<gblk, 256, 0, stream>>>(aob, wob, bo, 1.f, out, (int)MTOK, DIMSZ, DIMSZ);
}

// Round 2
// 168.376 us; speedup vs baseline: 1.2302x; 1.2302x over previous
//
#include <hip/hip_runtime.h>
#include <hip/hip_bf16.h>
#include <math.h>

typedef __bf16 bf16;
typedef __bf16 bf16x8 __attribute__((ext_vector_type(8)));
typedef __bf16 bf16x4 __attribute__((ext_vector_type(4)));
typedef float f32x4 __attribute__((ext_vector_type(4)));

#define SEQ 1024
#define DIMSZ 1024
#define NHEADS 16
#define HEADDIM 64
#define BATCH 4

// ---------------- fp32 -> bf16 conversion (optionally scaled) ----------------
__global__ void cvt_f32_bf16(const float4* __restrict__ src, bf16x4* __restrict__ dst,
                             int n4, float scale) {
    int i = blockIdx.x * blockDim.x + threadIdx.x;
    if (i < n4) {
        float4 v = src[i];
        bf16x4 o;
        o[0] = (bf16)(v.x * scale);
        o[1] = (bf16)(v.y * scale);
        o[2] = (bf16)(v.z * scale);
        o[3] = (bf16)(v.w * scale);
        dst[i] = o;
    }
}

// LDS fragment read: 8 contiguous bf16 at [row0 + (lane&15)][k0 + (lane>>4)*8],
// leading dim 72 elements (144B rows, 16B-aligned, 2-way bank conflicts = free).
#define LDT 72
__device__ inline bf16x8 ldsfrag(const bf16* base, int row0, int k0, int lane) {
    return *reinterpret_cast<const bf16x8*>(base + (row0 + (lane & 15)) * LDT + k0 + ((lane >> 4) << 3));
}

// ---------------- bf16 GEMM: C[M][N] = A[M][K] @ B[N][K]^T + bias ----------------
template <int OUT_F32>
__global__ __launch_bounds__(256) void gemm_bt(
    const bf16* __restrict__ A, const bf16* __restrict__ Bm,
    const float* __restrict__ bias, float bias_scale,
    void* __restrict__ Cv, int M, int N, int K)
{
    __shared__ __align__(16) bf16 As[128 * LDT];
    __shared__ __align__(16) bf16 Bs[128 * LDT];

    const int nbn = N >> 7;
    const int bm = blockIdx.x / nbn, bn = blockIdx.x % nbn;
    const int m0 = bm << 7, n0 = bn << 7;
    const int tid = threadIdx.x, lane = tid & 63, wid = tid >> 6;
    const int wr = wid >> 1, wc = wid & 1;

    f32x4 acc[4][4] = {};

    for (int kt = 0; kt < K; kt += 64) {
        #pragma unroll
        for (int c = 0; c < 4; ++c) {
            int id = tid + (c << 8);
            int row = id >> 3, c8 = (id & 7) << 3;
            *reinterpret_cast<bf16x8*>(&As[row * LDT + c8]) =
                *reinterpret_cast<const bf16x8*>(&A[(size_t)(m0 + row) * K + kt + c8]);
            *reinterpret_cast<bf16x8*>(&Bs[row * LDT + c8]) =
                *reinterpret_cast<const bf16x8*>(&Bm[(size_t)(n0 + row) * K + kt + c8]);
        }
        __syncthreads();

        bf16x8 af[4][2], bfr[4][2];
        #pragma unroll
        for (int m = 0; m < 4; ++m)
            #pragma unroll
            for (int h2 = 0; h2 < 2; ++h2)
                af[m][h2] = ldsfrag(As, wr * 64 + m * 16, h2 * 32, lane);
        #pragma unroll
        for (int n = 0; n < 4; ++n)
            #pragma unroll
            for (int h2 = 0; h2 < 2; ++h2)
                bfr[n][h2] = ldsfrag(Bs, wc * 64 + n * 16, h2 * 32, lane);

        #pragma unroll
        for (int m = 0; m < 4; ++m)
            #pragma unroll
            for (int n = 0; n < 4; ++n)
                #pragma unroll
                for (int h2 = 0; h2 < 2; ++h2)
                    acc[m][n] = __builtin_amdgcn_mfma_f32_16x16x32_bf16(
                        af[m][h2], bfr[n][h2], acc[m][n], 0, 0, 0);
        __syncthreads();
    }

    #pragma unroll
    for (int m = 0; m < 4; ++m) {
        #pragma unroll
        for (int n = 0; n < 4; ++n) {
            int rbase = m0 + wr * 64 + m * 16 + ((lane >> 4) << 2);
            int col = n0 + wc * 64 + n * 16 + (lane & 15);
            float bv = bias[col] * bias_scale;
            #pragma unroll
            for (int r = 0; r < 4; ++r) {
                float v = acc[m][n][r] + bv;
                if (OUT_F32)
                    ((float*)Cv)[(size_t)(rbase + r) * N + col] = v;
                else
                    ((bf16*)Cv)[(size_t)(rbase + r) * N + col] = (bf16)v;
            }
        }
    }
}

// ---------------- fused decay-masked attention, batch-pair fused ----------------
// 512 blocks = (h, qblk64, batch-pair), 256 threads (4 waves x 16 q-rows).
// Swapped QK^T (S^T: col=lane&15=q) -> mask as float4 regs, 2-shfl softmax,
// vectorized P writes. V^T staged with XOR swizzle (conflict-free-ish).
// Work-mapping puts the two batch-pair blocks of one (h,qblk) on the same XCD.
__global__ __launch_bounds__(256) void attn_kernel(
    const bf16* __restrict__ Qg, const bf16* __restrict__ Kg, const bf16* __restrict__ Vg,
    const float* __restrict__ mask, bf16* __restrict__ Og)
{
    __shared__ __align__(16) bf16 Ks[2][64 * LDT];
    __shared__ __align__(16) bf16 VTs[2][64 * LDT];  // [d][k], XOR-swizzled
    __shared__ __align__(16) bf16 Ps[4][16 * LDT];   // per-wave P strip [q][k]

    // work mapping: bid = xcd + 8*(2*pair_local + bp); pg = xcd*32 + pair_local
    const int bid = blockIdx.x;
    const int xcd = bid & 7, slot = bid >> 3;
    const int pg = xcd * 32 + (slot >> 1);   // 0..255 = (h, qblk)
    const int bp = slot & 1;                 // batch pair: {2bp, 2bp+1}
    const int h = pg >> 4, qblk = pg & 15;

    const int tid = threadIdx.x, lane = tid & 63, wid = tid >> 6;
    const int lq = lane & 15, g = lane >> 4;
    const int q = (qblk << 6) + wid * 16 + lq;        // this lane's q row
    const float* mh = mask + (size_t)h * SEQ * SEQ + (size_t)q * SEQ;

    // Q fragments in registers (q pre-scaled by 1/8 via wq)
    bf16x8 aq[2][2];
    #pragma unroll
    for (int bi = 0; bi < 2; ++bi)
        #pragma unroll
        for (int h2 = 0; h2 < 2; ++h2)
            aq[bi][h2] = *reinterpret_cast<const bf16x8*>(
                &Qg[(size_t)((bp * 2 + bi) * SEQ + q) * DIMSZ + h * HEADDIM + h2 * 32 + g * 8]);

    float m_run[2] = {-3.0e38f, -3.0e38f};
    float l_run[2] = {0.f, 0.f};
    f32x4 oacc[2][4] = {};   // O^T: row d = ot*16+g*4+r, col q = lq

    const int kr = tid >> 3;          // staging row 0..31 (+c*32)
    const int d0 = (tid & 7) << 3;    // staging col octet

    for (int kt = 0; kt < SEQ; kt += 64) {
        // mask tile into registers: element (ct,r) = mh[kt + ct*16 + g*4 + r]
        float4 mreg[4];
        #pragma unroll
        for (int ct = 0; ct < 4; ++ct)
            mreg[ct] = *reinterpret_cast<const float4*>(&mh[kt + ct * 16 + g * 4]);

        // stage K (row-major) and V^T (XOR-swizzled) for both batches
        #pragma unroll
        for (int c = 0; c < 2; ++c) {
            int row = kr + c * 32;
            #pragma unroll
            for (int bi = 0; bi < 2; ++bi) {
                size_t gofs = (size_t)((bp * 2 + bi) * SEQ + kt + row) * DIMSZ + h * HEADDIM + d0;
                *reinterpret_cast<bf16x8*>(&Ks[bi][row * LDT + d0]) =
                    *reinterpret_cast<const bf16x8*>(&Kg[gofs]);
                bf16x8 v8 = *reinterpret_cast<const bf16x8*>(&Vg[gofs]);
                #pragma unroll
                for (int j = 0; j < 8; ++j) {
                    int d = d0 + j;
                    int byteo = (d * 144 + row * 2) ^ (((d >> 3) & 7) << 4);
                    *reinterpret_cast<bf16*>(reinterpret_cast<char*>(VTs[bi]) + byteo) = v8[j];
                }
            }
        }
        __syncthreads();

        #pragma unroll
        for (int bi = 0; bi < 2; ++bi) {
            // S^T strip: rows k (ct*16+g*4+r), col q=lq
            f32x4 sacc[4] = {};
            #pragma unroll
            for (int ct = 0; ct < 4; ++ct)
                #pragma unroll
                for (int h2 = 0; h2 < 2; ++h2)
                    sacc[ct] = __builtin_amdgcn_mfma_f32_16x16x32_bf16(
                        ldsfrag(Ks[bi], ct * 16, h2 * 32, lane), aq[bi][h2], sacc[ct], 0, 0, 0);

            // mask multiply (register-aligned) + row max (this lane owns one q-row)
            float sv[4][4];
            float mx = -3.0e38f;
            #pragma unroll
            for (int ct = 0; ct < 4; ++ct) {
                sv[ct][0] = sacc[ct][0] * mreg[ct].x;
                sv[ct][1] = sacc[ct][1] * mreg[ct].y;
                sv[ct][2] = sacc[ct][2] * mreg[ct].z;
                sv[ct][3] = sacc[ct][3] * mreg[ct].w;
                #pragma unroll
                for (int r = 0; r < 4; ++r) mx = fmaxf(mx, sv[ct][r]);
            }
            mx = fmaxf(mx, __shfl_xor(mx, 16, 64));
            mx = fmaxf(mx, __shfl_xor(mx, 32, 64));
            float mnew = fmaxf(m_run[bi], mx);
            float scl = __expf(m_run[bi] - mnew);

            float sum = 0.f;
            float pl[4][4];
            #pragma unroll
            for (int ct = 0; ct < 4; ++ct)
                #pragma unroll
                for (int r = 0; r < 4; ++r) {
                    float p = __expf(sv[ct][r] - mnew);
                    pl[ct][r] = p;
                    sum += p;
                }
            sum += __shfl_xor(sum, 16, 64);
            sum += __shfl_xor(sum, 32, 64);
            l_run[bi] = l_run[bi] * scl + sum;
            m_run[bi] = mnew;
            #pragma unroll
            for (int ot = 0; ot < 4; ++ot) {
                oacc[bi][ot][0] *= scl; oacc[bi][ot][1] *= scl;
                oacc[bi][ot][2] *= scl; oacc[bi][ot][3] *= scl;
            }

            // P -> LDS (wave-private strip, 8B vector writes): Ps[wid][q=lq][k]
            #pragma unroll
            for (int ct = 0; ct < 4; ++ct) {
                bf16x4 pb;
                pb[0] = (bf16)pl[ct][0]; pb[1] = (bf16)pl[ct][1];
                pb[2] = (bf16)pl[ct][2]; pb[3] = (bf16)pl[ct][3];
                *reinterpret_cast<bf16x4*>(&Ps[wid][lq * LDT + ct * 16 + g * 4]) = pb;
            }

            // O^T += mfma(V^T rows d, P rows q)  (same-wave ds ordering via lgkmcnt)
            #pragma unroll
            for (int ot = 0; ot < 4; ++ot) {
                #pragma unroll
                for (int h2 = 0; h2 < 2; ++h2) {
                    int d = ot * 16 + lq;
                    int byteo = (d * 144 + (h2 * 32 + g * 8) * 2) ^ (((d >> 3) & 7) << 4);
                    bf16x8 vf = *reinterpret_cast<const bf16x8*>(
                        reinterpret_cast<const char*>(VTs[bi]) + byteo);
                    bf16x8 pf = *reinterpret_cast<const bf16x8*>(
                        &Ps[wid][lq * LDT + h2 * 32 + g * 8]);
                    oacc[bi][ot] = __builtin_amdgcn_mfma_f32_16x16x32_bf16(
                        vf, pf, oacc[bi][ot], 0, 0, 0);
                }
            }
        }
        __syncthreads();
    }

    // epilogue: O[q][d] = O^T/l ; 8B stores
    #pragma unroll
    for (int bi = 0; bi < 2; ++bi) {
        float inv = 1.f / l_run[bi];
        #pragma unroll
        for (int ot = 0; ot < 4; ++ot) {
            bf16x4 o;
            o[0] = (bf16)(oacc[bi][ot][0] * inv);
            o[1] = (bf16)(oacc[bi][ot][1] * inv);
            o[2] = (bf16)(oacc[bi][ot][2] * inv);
            o[3] = (bf16)(oacc[bi][ot][3] * inv);
            *reinterpret_cast<bf16x4*>(
                &Og[(size_t)((bp * 2 + bi) * SEQ + q) * DIMSZ + h * HEADDIM + ot * 16 + g * 4]) = o;
        }
    }
}

extern "C" void kernel_launch(void* const* d_in, const int* in_sizes, int n_in,
                              void* d_out, int out_size, void* d_ws, size_t ws_size,
                              hipStream_t stream) {
    const float* x    = (const float*)d_in[0];
    const float* mask = (const float*)d_in[1];
    const float* wq   = (const float*)d_in[2];
    const float* bq   = (const float*)d_in[3];
    const float* wk   = (const float*)d_in[4];
    const float* bk   = (const float*)d_in[5];
    const float* wv   = (const float*)d_in[6];
    const float* bv   = (const float*)d_in[7];
    const float* wo   = (const float*)d_in[8];
    const float* bo   = (const float*)d_in[9];
    float* out = (float*)d_out;

    const size_t MTOK = (size_t)BATCH * SEQ;           // 4096
    char* ws = (char*)d_ws;
    bf16* xb  = (bf16*)ws; ws += MTOK * DIMSZ * 2;     // 8 MB
    bf16* wqb = (bf16*)ws; ws += (size_t)DIMSZ * DIMSZ * 2;
    bf16* wkb = (bf16*)ws; ws += (size_t)DIMSZ * DIMSZ * 2;
    bf16* wvb = (bf16*)ws; ws += (size_t)DIMSZ * DIMSZ * 2;
    bf16* wob = (bf16*)ws; ws += (size_t)DIMSZ * DIMSZ * 2;
    bf16* qb  = (bf16*)ws; ws += MTOK * DIMSZ * 2;
    bf16* kb  = (bf16*)ws; ws += MTOK * DIMSZ * 2;
    bf16* vb  = (bf16*)ws; ws += MTOK * DIMSZ * 2;
    bf16* aob = (bf16*)ws; ws += MTOK * DIMSZ * 2;     // total 48 MB

    int n4x = (int)(MTOK * DIMSZ / 4);
    cvt_f32_bf16<<<(n4x + 255) / 256, 256, 0, stream>>>((const float4*)x, (bf16x4*)xb, n4x, 1.f);
    int n4w = DIMSZ * DIMSZ / 4;
    int gw = (n4w + 255) / 256;
    cvt_f32_bf16<<<gw, 256, 0, stream>>>((const float4*)wq, (bf16x4*)wqb, n4w, 0.125f);
    cvt_f32_bf16<<<gw, 256, 0, stream>>>((const float4*)wk, (bf16x4*)wkb, n4w, 1.f);
    cvt_f32_bf16<<<gw, 256, 0, stream>>>((const float4*)wv, (bf16x4*)wvb, n4w, 1.f);
    cvt_f32_bf16<<<gw, 256, 0, stream>>>((const float4*)wo, (bf16x4*)wob, n4w, 1.f);

    int gblk = (int)(MTOK / 128) * (DIMSZ / 128);  // 256
    gemm_bt<0><<<gblk, 256, 0, stream>>>(xb, wqb, bq, 0.125f, qb, (int)MTOK, DIMSZ, DIMSZ);
    gemm_bt<0><<<gblk, 256, 0, stream>>>(xb, wkb, bk, 1.f, kb, (int)MTOK, DIMSZ, DIMSZ);
    gemm_bt<0><<<gblk, 256, 0, stream>>>(xb, wvb, bv, 1.f, vb, (int)MTOK, DIMSZ, DIMSZ);

    attn_kernel<<<512, 256, 0, stream>>>(qb, kb, vb, mask, aob);

    gemm_bt<1><<<gblk, 256, 0, stream>>>(aob, wob, bo, 1.f, out, (int)MTOK, DIMSZ, DIMSZ);
}

// Round 3
// 120.130 us; speedup vs baseline: 1.7243x; 1.4016x over previous
//
#include <hip/hip_runtime.h>
#include <hip/hip_bf16.h>
#include <math.h>

typedef __bf16 bf16;
typedef __bf16 bf16x8 __attribute__((ext_vector_type(8)));
typedef __bf16 bf16x4 __attribute__((ext_vector_type(4)));
typedef float f32x4 __attribute__((ext_vector_type(4)));
typedef unsigned short u16;
typedef u16 u16x8 __attribute__((ext_vector_type(8)));

#define SEQ 1024
#define DIMSZ 1024
#define NHEADS 16
#define HEADDIM 64
#define BATCH 4

// ---------------- async global->LDS (16B per lane, linear dest) ----------------
typedef __attribute__((address_space(1))) const unsigned char gas_u8;
typedef __attribute__((address_space(3))) unsigned char las_u8;
__device__ __forceinline__ void gload16(const void* g, void* l) {
    __builtin_amdgcn_global_load_lds((const gas_u8*)g, (las_u8*)l, 16, 0, 0);
}

// ---------------- fp32 -> bf16 conversion with baked chunk-swizzle ----------------
// dst element (row, col) stored at col' = swap 16B-chunks: chunk ^= (row&7)
// (all matrices here have 1024 columns)
__global__ void cvt_swz(const float4* __restrict__ src, bf16* __restrict__ dst,
                        int n4, float scale) {
    int i = blockIdx.x * blockDim.x + threadIdx.x;
    if (i >= n4) return;
    float4 v = src[i];
    int e0 = i << 2;
    int row = e0 >> 10, col = e0 & 1023;
    int col2 = (col & ~63) | (col & 7) | (((((col >> 3) & 7) ^ (row & 7))) << 3);
    bf16x4 o;
    o[0] = (bf16)(v.x * scale);
    o[1] = (bf16)(v.y * scale);
    o[2] = (bf16)(v.z * scale);
    o[3] = (bf16)(v.w * scale);
    *reinterpret_cast<bf16x4*>(&dst[(size_t)row * 1024 + col2]) = o;
}

// swizzled LDS fragment read from linear [rows][64] bf16 tile:
// 8 contiguous bf16 of (row, kbyte..) with chunk-XOR de-swizzle
__device__ __forceinline__ bf16x8 fragswz(const bf16* base, int row, int kb) {
    return *reinterpret_cast<const bf16x8*>(
        reinterpret_cast<const char*>(base) + row * 128 + (kb ^ ((row & 7) << 4)));
}

// padded-LDS fragment read (LDT=72 rows) used by attn
#define LDT 72
__device__ __forceinline__ bf16x8 ldsfrag72(const bf16* base, int row0, int k0, int lane) {
    return *reinterpret_cast<const bf16x8*>(base + (row0 + (lane & 15)) * LDT + k0 + ((lane >> 4) << 3));
}

// ---------------- m97-style GEMM: C[M][N] = A[M][K] @ B[N][K]^T + bias ----------------
// A, B stored pre-swizzled (cvt_swz / attn epilogue). BM=128, BN=WN*32, BK=64.
// 256 threads; wave (wr,wc) owns 64 x (WN*16) quadrant, acc[4][WN].
template <int WN, int OUT_F32>
__global__ __launch_bounds__(256) void gemm_glds(
    const bf16* __restrict__ A, const bf16* __restrict__ Bm,
    const float* __restrict__ b0, const float* __restrict__ b1, const float* __restrict__ b2,
    float s0, void* __restrict__ Cv, int M, int N, int K)
{
    __shared__ __align__(16) bf16 As[128 * 64];
    __shared__ __align__(16) bf16 Bs[WN * 32 * 64];

    const int BN = WN * 32;
    const int nbn = N / BN;
    const int bm = blockIdx.x / nbn, bn = blockIdx.x % nbn;
    const int m0 = bm << 7, n0 = bn * BN;
    const int tid = threadIdx.x, lane = tid & 63, wid = tid >> 6;
    const int wr = wid >> 1, wc = wid & 1;
    const int lq = lane & 15, g = lane >> 4;

    f32x4 acc[4][WN];
    #pragma unroll
    for (int m = 0; m < 4; ++m)
        #pragma unroll
        for (int n = 0; n < WN; ++n)
            acc[m][n] = (f32x4){0.f, 0.f, 0.f, 0.f};

    for (int kt = 0; kt < K; kt += 64) {
        // stage A (128x64) + B (BNx64) via global_load_lds, linear LDS
        #pragma unroll
        for (int i = 0; i < 4; ++i) {
            int rb = wid * 32 + i * 8;
            gload16(&A[(size_t)(m0 + rb + (lane >> 3)) * K + kt + ((lane & 7) << 3)],
                    &As[rb * 64]);
        }
        #pragma unroll
        for (int i = 0; i < WN; ++i) {
            int rb = wid * (WN * 8) + i * 8;
            gload16(&Bm[(size_t)(n0 + rb + (lane >> 3)) * K + kt + ((lane & 7) << 3)],
                    &Bs[rb * 64]);
        }
        __syncthreads();

        bf16x8 af[4][2], bfr[WN][2];
        #pragma unroll
        for (int m = 0; m < 4; ++m)
            #pragma unroll
            for (int h2 = 0; h2 < 2; ++h2)
                af[m][h2] = fragswz(As, wr * 64 + m * 16 + lq, h2 * 64 + g * 16);
        #pragma unroll
        for (int n = 0; n < WN; ++n)
            #pragma unroll
            for (int h2 = 0; h2 < 2; ++h2)
                bfr[n][h2] = fragswz(Bs, wc * (WN * 16) + n * 16 + lq, h2 * 64 + g * 16);

        #pragma unroll
        for (int m = 0; m < 4; ++m)
            #pragma unroll
            for (int n = 0; n < WN; ++n)
                #pragma unroll
                for (int h2 = 0; h2 < 2; ++h2)
                    acc[m][n] = __builtin_amdgcn_mfma_f32_16x16x32_bf16(
                        af[m][h2], bfr[n][h2], acc[m][n], 0, 0, 0);
        __syncthreads();
    }

    // bias select (wave-uniform per block)
    const int seg = n0 >> 10;
    const float* bp = (seg == 0) ? b0 : ((seg == 1) ? b1 : b2);
    const float bsc = (seg == 0) ? s0 : 1.f;

    #pragma unroll
    for (int m = 0; m < 4; ++m) {
        #pragma unroll
        for (int n = 0; n < WN; ++n) {
            int rbase = m0 + wr * 64 + m * 16 + (g << 2);
            int col = n0 + wc * (WN * 16) + n * 16 + lq;
            float bv = bp[col - (seg << 10)] * bsc;
            #pragma unroll
            for (int r = 0; r < 4; ++r) {
                float v = acc[m][n][r] + bv;
                if (OUT_F32)
                    ((float*)Cv)[(size_t)(rbase + r) * N + col] = v;
                else
                    ((bf16*)Cv)[(size_t)(rbase + r) * N + col] = (bf16)v;
            }
        }
    }
}

// ---------------- fused decay-masked attention, pipelined ----------------
struct KVRegs { bf16x8 k0, k1; u16x8 v0, v1; };

__device__ __forceinline__ void issue_loads(KVRegs& r, const bf16* qkv, int brow,
                                            int koff, int voff, int tid) {
    const int rK = tid >> 3, o8 = (tid & 7) << 3;
    r.k0 = *reinterpret_cast<const bf16x8*>(&qkv[(size_t)(brow + rK) * 3072 + koff + o8]);
    r.k1 = *reinterpret_cast<const bf16x8*>(&qkv[(size_t)(brow + rK + 32) * 3072 + koff + o8]);
    const int rV = rK << 1;
    r.v0 = *reinterpret_cast<const u16x8*>(&qkv[(size_t)(brow + rV) * 3072 + voff + o8]);
    r.v1 = *reinterpret_cast<const u16x8*>(&qkv[(size_t)(brow + rV + 1) * 3072 + voff + o8]);
}

__device__ __forceinline__ void write_stage(const KVRegs& r, bf16* Kb, bf16* Vb, int tid) {
    const int rK = tid >> 3, o = tid & 7, o8 = o << 3;
    *reinterpret_cast<bf16x8*>(&Kb[rK * LDT + o8]) = r.k0;
    *reinterpret_cast<bf16x8*>(&Kb[(rK + 32) * LDT + o8]) = r.k1;
    const int rV = rK << 1;
    #pragma unroll
    for (int j = 0; j < 8; ++j) {
        int d = o8 + j;
        int byteo = (d * 144 + rV * 2) ^ (o << 4);
        unsigned int w = (unsigned int)r.v0[j] | ((unsigned int)r.v1[j] << 16);
        *reinterpret_cast<unsigned int*>(reinterpret_cast<char*>(Vb) + byteo) = w;
    }
}

__device__ __forceinline__ void compute_stage(
    const bf16* Kb, const bf16* Vb, bf16* Psw,
    const float4 (&mreg)[4], const bf16x8 (&aqb)[2],
    float& m_run, float& l_run, f32x4 (&oacc)[4], int lane)
{
    const int lq = lane & 15, g = lane >> 4;
    f32x4 sacc[4];
    #pragma unroll
    for (int ct = 0; ct < 4; ++ct) sacc[ct] = (f32x4){0.f, 0.f, 0.f, 0.f};
    #pragma unroll
    for (int ct = 0; ct < 4; ++ct)
        #pragma unroll
        for (int h2 = 0; h2 < 2; ++h2)
            sacc[ct] = __builtin_amdgcn_mfma_f32_16x16x32_bf16(
                ldsfrag72(Kb, ct * 16, h2 * 32, lane), aqb[h2], sacc[ct], 0, 0, 0);

    float sv[4][4];
    float mx = -3.0e38f;
    #pragma unroll
    for (int ct = 0; ct < 4; ++ct) {
        sv[ct][0] = sacc[ct][0] * mreg[ct].x;
        sv[ct][1] = sacc[ct][1] * mreg[ct].y;
        sv[ct][2] = sacc[ct][2] * mreg[ct].z;
        sv[ct][3] = sacc[ct][3] * mreg[ct].w;
        mx = fmaxf(mx, fmaxf(fmaxf(sv[ct][0], sv[ct][1]), fmaxf(sv[ct][2], sv[ct][3])));
    }
    mx = fmaxf(mx, __shfl_xor(mx, 16, 64));
    mx = fmaxf(mx, __shfl_xor(mx, 32, 64));

    // defer-max (THR=8): only rescale when the max actually grows
    if (!__all(mx <= m_run + 8.f)) {
        float mnew = fmaxf(m_run, mx);
        float scl = __expf(m_run - mnew);
        l_run *= scl;
        #pragma unroll
        for (int ot = 0; ot < 4; ++ot) oacc[ot] *= scl;
        m_run = mnew;
    }

    float sum = 0.f;
    float pl[4][4];
    #pragma unroll
    for (int ct = 0; ct < 4; ++ct)
        #pragma unroll
        for (int r = 0; r < 4; ++r) {
            float p = __expf(sv[ct][r] - m_run);
            pl[ct][r] = p;
            sum += p;
        }
    sum += __shfl_xor(sum, 16, 64);
    sum += __shfl_xor(sum, 32, 64);
    l_run += sum;

    #pragma unroll
    for (int ct = 0; ct < 4; ++ct) {
        bf16x4 pb;
        pb[0] = (bf16)pl[ct][0]; pb[1] = (bf16)pl[ct][1];
        pb[2] = (bf16)pl[ct][2]; pb[3] = (bf16)pl[ct][3];
        *reinterpret_cast<bf16x4*>(&Psw[lq * LDT + ct * 16 + (g << 2)]) = pb;
    }

    #pragma unroll
    for (int ot = 0; ot < 4; ++ot) {
        #pragma unroll
        for (int h2 = 0; h2 < 2; ++h2) {
            int d = ot * 16 + lq;
            int byteo = (d * 144 + (h2 * 32 + g * 8) * 2) ^ (((d >> 3) & 7) << 4);
            bf16x8 vf = *reinterpret_cast<const bf16x8*>(
                reinterpret_cast<const char*>(Vb) + byteo);
            bf16x8 pf = *reinterpret_cast<const bf16x8*>(&Psw[lq * LDT + h2 * 32 + g * 8]);
            oacc[ot] = __builtin_amdgcn_mfma_f32_16x16x32_bf16(vf, pf, oacc[ot], 0, 0, 0);
        }
    }
}

// 512 blocks = (h, qblk64, batch-pair); 4 waves x 16 q-rows; 32-stage pipeline,
// one barrier per stage; output written chunk-swizzled for the final GEMM.
__global__ __launch_bounds__(256) void attn_kernel(
    const bf16* __restrict__ qkv, const float* __restrict__ mask, bf16* __restrict__ Og)
{
    __shared__ __align__(16) bf16 Kbuf[2][64 * LDT];
    __shared__ __align__(16) bf16 Vbuf[2][64 * LDT];
    __shared__ __align__(16) bf16 Ps[4][16 * LDT];

    const int bid = blockIdx.x;
    const int xcd = bid & 7, slot = bid >> 3;
    const int pg = xcd * 32 + (slot >> 1);
    const int bp = slot & 1;
    const int h = pg >> 4, qblk = pg & 15;

    const int tid = threadIdx.x, lane = tid & 63, wid = tid >> 6;
    const int lq = lane & 15, g = lane >> 4;
    const int q = (qblk << 6) + wid * 16 + lq;
    const int koff = 1024 + h * HEADDIM, voff = 2048 + h * HEADDIM, qoff = h * HEADDIM;
    const float* mh = mask + (size_t)h * SEQ * SEQ + (size_t)q * SEQ;

    // Q fragments (pre-scaled by 1/8 via wq)
    bf16x8 aq[2][2];
    #pragma unroll
    for (int bi = 0; bi < 2; ++bi)
        #pragma unroll
        for (int h2 = 0; h2 < 2; ++h2)
            aq[bi][h2] = *reinterpret_cast<const bf16x8*>(
                &qkv[(size_t)((bp * 2 + bi) * SEQ + q) * 3072 + qoff + h2 * 32 + g * 8]);

    float m_run[2] = {-3.0e38f, -3.0e38f};
    float l_run[2] = {0.f, 0.f};
    f32x4 oacc[2][4] = {};

    // prologue: stage 0 and 1 loads, mask tiles 0 and 1
    KVRegs s0, s1;
    issue_loads(s0, qkv, (bp * 2 + 0) * SEQ, koff, voff, tid);
    issue_loads(s1, qkv, (bp * 2 + 1) * SEQ, koff, voff, tid);
    float4 mregA[4], mregB[4];
    #pragma unroll
    for (int ct = 0; ct < 4; ++ct) {
        mregA[ct] = *reinterpret_cast<const float4*>(&mh[ct * 16 + (g << 2)]);
        mregB[ct] = *reinterpret_cast<const float4*>(&mh[64 + ct * 16 + (g << 2)]);
    }
    write_stage(s0, Kbuf[0], Vbuf[0], tid);
    __syncthreads();

    for (int t = 0; t < 16; ++t) {
        // --- stage (t, bi=0) from buf0 ---
        if (t < 15) issue_loads(s0, qkv, (bp * 2 + 0) * SEQ + (t + 1) * 64, koff, voff, tid);
        compute_stage(Kbuf[0], Vbuf[0], Ps[wid], mregA, aq[0],
                      m_run[0], l_run[0], oacc[0], lane);
        write_stage(s1, Kbuf[1], Vbuf[1], tid);
        __syncthreads();

        // --- stage (t, bi=1) from buf1 ---
        if (t < 15) issue_loads(s1, qkv, (bp * 2 + 1) * SEQ + (t + 1) * 64, koff, voff, tid);
        compute_stage(Kbuf[1], Vbuf[1], Ps[wid], mregA, aq[1],
                      m_run[1], l_run[1], oacc[1], lane);
        #pragma unroll
        for (int ct = 0; ct < 4; ++ct) mregA[ct] = mregB[ct];
        if (t < 14)
            #pragma unroll
            for (int ct = 0; ct < 4; ++ct)
                mregB[ct] = *reinterpret_cast<const float4*>(&mh[(t + 2) * 64 + ct * 16 + (g << 2)]);
        if (t < 15) write_stage(s0, Kbuf[0], Vbuf[0], tid);
        __syncthreads();
    }

    // epilogue: O[q][d] = O^T/l, stored chunk-swizzled (consumed by gemm_glds)
    #pragma unroll
    for (int bi = 0; bi < 2; ++bi) {
        float inv = 1.f / l_run[bi];
        #pragma unroll
        for (int ot = 0; ot < 4; ++ot) {
            bf16x4 o;
            o[0] = (bf16)(oacc[bi][ot][0] * inv);
            o[1] = (bf16)(oacc[bi][ot][1] * inv);
            o[2] = (bf16)(oacc[bi][ot][2] * inv);
            o[3] = (bf16)(oacc[bi][ot][3] * inv);
            int lcol = ot * 16 + (g << 2);
            int chunk = (lcol >> 3) ^ (q & 7);
            int col = h * HEADDIM + (chunk << 3) + (lcol & 7);
            *reinterpret_cast<bf16x4*>(
                &Og[(size_t)((bp * 2 + bi) * SEQ + q) * DIMSZ + col]) = o;
        }
    }
}

extern "C" void kernel_launch(void* const* d_in, const int* in_sizes, int n_in,
                              void* d_out, int out_size, void* d_ws, size_t ws_size,
                              hipStream_t stream) {
    const float* x    = (const float*)d_in[0];
    const float* mask = (const float*)d_in[1];
    const float* wq   = (const float*)d_in[2];
    const float* bq   = (const float*)d_in[3];
    const float* wk   = (const float*)d_in[4];
    const float* bk   = (const float*)d_in[5];
    const float* wv   = (const float*)d_in[6];
    const float* bv   = (const float*)d_in[7];
    const float* wo   = (const float*)d_in[8];
    const float* bo   = (const float*)d_in[9];
    float* out = (float*)d_out;

    const size_t MTOK = (size_t)BATCH * SEQ;             // 4096
    char* ws = (char*)d_ws;
    bf16* xb    = (bf16*)ws; ws += MTOK * DIMSZ * 2;                 // 8 MB
    bf16* wqkvb = (bf16*)ws; ws += (size_t)3 * DIMSZ * DIMSZ * 2;    // 6 MB
    bf16* wob   = (bf16*)ws; ws += (size_t)DIMSZ * DIMSZ * 2;        // 2 MB
    bf16* qkv   = (bf16*)ws; ws += MTOK * 3 * DIMSZ * 2;             // 24 MB
    bf16* aob   = (bf16*)ws; ws += MTOK * DIMSZ * 2;                 // 8 MB -> 48 MB total

    // conversions with baked swizzle (fold 1/8 into wq, bq)
    int n4x = (int)(MTOK * DIMSZ / 4);
    cvt_swz<<<(n4x + 255) / 256, 256, 0, stream>>>((const float4*)x, xb, n4x, 1.f);
    int n4w = DIMSZ * DIMSZ / 4;
    int gw = (n4w + 255) / 256;
    cvt_swz<<<gw, 256, 0, stream>>>((const float4*)wq, wqkvb,                 n4w, 0.125f);
    cvt_swz<<<gw, 256, 0, stream>>>((const float4*)wk, wqkvb + 1024 * 1024,   n4w, 1.f);
    cvt_swz<<<gw, 256, 0, stream>>>((const float4*)wv, wqkvb + 2 * 1024 * 1024, n4w, 1.f);
    cvt_swz<<<gw, 256, 0, stream>>>((const float4*)wo, wob,                   n4w, 1.f);

    // fused QKV projection: [4096,1024] @ [3072,1024]^T -> [4096,3072]
    gemm_glds<4, 0><<<(MTOK / 128) * (3 * DIMSZ / 128), 256, 0, stream>>>(
        xb, wqkvb, bq, bk, bv, 0.125f, qkv, (int)MTOK, 3 * DIMSZ, DIMSZ);

    // fused attention
    attn_kernel<<<512, 256, 0, stream>>>(qkv, mask, aob);

    // output projection: [4096,1024] @ [1024,1024]^T -> [4096,1024] fp32
    gemm_glds<2, 1><<<(MTOK / 128) * (DIMSZ / 64), 256, 0, stream>>>(
        aob, wob, bo, bo, bo, 1.f, out, (int)MTOK, DIMSZ, DIMSZ);
}